// Round 8
// baseline (147.145 us; speedup 1.0000x reference)
//
#include <hip/hip_runtime.h>

#define BATCH 16384
#define CTX 10
#define MAXC 24
#define ROWS_PER_BLOCK 4              // 2 waves * 2 rows per wave
#define GRID_MAIN (BATCH / ROWS_PER_BLOCK)   // 4096 blocks

// R8: force the gather pipeline the compiler refused to build in R7.
// All 34 row-gathers (10 ctx + 24 path) are issued, then
// sched_barrier(0) pins them BEFORE any consumption -> ~136 VGPRs of loads
// stay in flight with incremental vmcnt waits (R7 kept VGPR=36, serialized).
// 128-thread blocks + __launch_bounds__(128,2) give the 256-VGPR budget.
__global__ __launch_bounds__(128, 2) void cbow_hs_main(
    const int* __restrict__ ctx_words,   // [B, CTX]
    const int* __restrict__ paths,       // [B, MAXC]
    const int* __restrict__ codes,       // [B, MAXC]
    const int* __restrict__ mask,        // [B, MAXC]
    const float* __restrict__ W_in,      // [VOCAB, 128]
    const float* __restrict__ W_internal,// [VOCAB-1, 128]
    float* __restrict__ partials)        // [GRID_MAIN]
{
    const int tid  = threadIdx.x;
    const int lane = tid & 63;
    const int half = lane >> 5;          // which row of the wave's pair
    const int l5   = lane & 31;          // lane within half-wave
    const int wave = tid >> 6;           // 0..1
    const int row  = blockIdx.x * ROWS_PER_BLOCK + wave * 2 + half;
    const int hbase = lane & 32;         // shfl source base for this half

    const float4* Win4 = (const float4*)W_in;        // 32 float4 per emb row
    const float4* Wn4  = (const float4*)W_internal;

    // ---- coalesced index prefetch: lane j (<24 / <10) of each half holds
    // index j for its row; broadcast via shfl ----
    int pidx = 0, cidx = 0;
    if (l5 < MAXC) pidx = paths[row * MAXC + l5];
    if (l5 < CTX)  cidx = ctx_words[row * CTX + l5];

    // ---- issue ALL 34 gathers before any consumption ----
    float4 ce[CTX];
#pragma unroll
    for (int k = 0; k < CTX; ++k) {
        const int w = __shfl(cidx, hbase + k, 64);
        ce[k] = Win4[(long)w * 32 + l5];             // 512B coalesced / half
    }
    float4 pe[MAXC];
#pragma unroll
    for (int l = 0; l < MAXC; ++l) {
        const int p = __shfl(pidx, hbase + l, 64);
        pe[l] = Wn4[(long)p * 32 + l5];
    }
    // scheduler fence: no instruction (esp. these loads) may cross.
    // Forces all 34 loads in flight; consumption below gets incremental
    // vmcnt(N) waits in issue order.
    __builtin_amdgcn_sched_barrier(0);

    // ---- context mean ----
    float4 acc = make_float4(0.f, 0.f, 0.f, 0.f);
#pragma unroll
    for (int k = 0; k < CTX; ++k) {
        acc.x += ce[k].x; acc.y += ce[k].y; acc.z += ce[k].z; acc.w += ce[k].w;
    }
    const float inv = 1.0f / (float)CTX;
    acc.x *= inv; acc.y *= inv; acc.z *= inv; acc.w *= inv;

    // ---- per-lane partial dots ----
    float part[MAXC];
#pragma unroll
    for (int l = 0; l < MAXC; ++l)
        part[l] = acc.x * pe[l].x + acc.y * pe[l].y
                + acc.z * pe[l].z + acc.w * pe[l].w;

    // ---- 5-step butterfly within each 32-lane half: every lane ends with
    // all 24 complete scores ----
#pragma unroll
    for (int off = 16; off; off >>= 1) {
#pragma unroll
        for (int l = 0; l < MAXC; ++l)
            part[l] += __shfl_xor(part[l], off, 64);
    }

    // ---- parallel masked loss: lane l5 (<24) handles node l5 ----
    float loss = 0.f;
    if (l5 < MAXC) {
        float s = 0.f;
#pragma unroll
        for (int l = 0; l < MAXC; ++l)               // compile-time extract
            if (l5 == l) s = part[l];
        const int c = codes[row * MAXC + l5];        // coalesced per-lane
        const int m = mask[row * MAXC + l5];
        const float z = c ? s : -s;                  // sign*score
        const float sp = fmaxf(-z, 0.f) + log1pf(expf(-fabsf(z)));
        loss = m ? sp : 0.f;
    }

    // ---- sum loss across the wave (covers both rows), LDS block reduce ----
#pragma unroll
    for (int off = 32; off; off >>= 1)
        loss += __shfl_xor(loss, off, 64);

    __shared__ float red[2];
    if (lane == 0) red[wave] = loss;
    __syncthreads();
    if (tid == 0)
        partials[blockIdx.x] = red[0] + red[1];
}

__global__ __launch_bounds__(256) void cbow_hs_reduce(
    const float* __restrict__ partials, float* __restrict__ out)
{
    const int tid = threadIdx.x;
    float s = 0.f;
#pragma unroll
    for (int i = 0; i < GRID_MAIN / 256; ++i)        // 16 each
        s += partials[tid + i * 256];
#pragma unroll
    for (int off = 32; off; off >>= 1)
        s += __shfl_xor(s, off, 64);
    __shared__ float red[4];
    if ((tid & 63) == 0) red[tid >> 6] = s;
    __syncthreads();
    if (tid == 0)
        out[0] = (red[0] + red[1] + red[2] + red[3]) * (1.0f / (float)BATCH);
}

extern "C" void kernel_launch(void* const* d_in, const int* in_sizes, int n_in,
                              void* d_out, int out_size, void* d_ws, size_t ws_size,
                              hipStream_t stream) {
    const int*   ctx_words  = (const int*)d_in[0];
    const int*   paths      = (const int*)d_in[1];
    const int*   codes      = (const int*)d_in[2];
    const int*   mask       = (const int*)d_in[3];
    const float* W_in       = (const float*)d_in[4];
    const float* W_internal = (const float*)d_in[5];
    float* out      = (float*)d_out;
    float* partials = (float*)d_ws;   // 4096 floats, fully written before read

    cbow_hs_main<<<GRID_MAIN, 128, 0, stream>>>(
        ctx_words, paths, codes, mask, W_in, W_internal, partials);
    cbow_hs_reduce<<<1, 256, 0, stream>>>(partials, out);
}